// Round 3
// baseline (3743.430 us; speedup 1.0000x reference)
//
#include <hip/hip_runtime.h>
#include <stdint.h>

#define N_NODES 50000
#define N_EDGES 1600000
#define NCB 13  // col blocks of 4096: 50000 -> 13

typedef __attribute__((ext_vector_type(8))) short bf16x8;
typedef __attribute__((ext_vector_type(4))) float f32x4;
typedef __attribute__((ext_vector_type(8))) unsigned short u16x8;

__device__ __forceinline__ float b2f(unsigned short u) {
  union { unsigned int i; float f; } v; v.i = ((unsigned int)u) << 16; return v.f;
}
__device__ __forceinline__ unsigned short f2b(float f) {
  union { float f; unsigned int i; } v; v.f = f;
  unsigned int u = v.i;
  u += 0x7fffu + ((u >> 16) & 1u);
  return (unsigned short)(u >> 16);
}

__device__ __forceinline__ void load_lds16(const void* g, void* l) {
  __builtin_amdgcn_global_load_lds(
      (const __attribute__((address_space(1))) unsigned int*)g,
      (__attribute__((address_space(3))) unsigned int*)l, 16, 0, 0);
}

// ---------------- row L2-normalize, fp32 -> bf16 ----------------
__global__ __launch_bounds__(256) void normalize_k(const float* __restrict__ x,
                                                   unsigned short* __restrict__ out) {
  int lane = threadIdx.x & 63;
  int row = blockIdx.x * 4 + (threadIdx.x >> 6);
  const float* p = x + (size_t)row * 512 + lane * 8;
  float4 a = ((const float4*)p)[0];
  float4 b = ((const float4*)p)[1];
  float ss = a.x*a.x + a.y*a.y + a.z*a.z + a.w*a.w
           + b.x*b.x + b.y*b.y + b.z*b.z + b.w*b.w;
#pragma unroll
  for (int off = 1; off < 64; off <<= 1) ss += __shfl_xor(ss, off, 64);
  float s = 1.0f / fmaxf(sqrtf(ss), 1e-12f);
  u16x8 o;
  o[0]=f2b(a.x*s); o[1]=f2b(a.y*s); o[2]=f2b(a.z*s); o[3]=f2b(a.w*s);
  o[4]=f2b(b.x*s); o[5]=f2b(b.y*s); o[6]=f2b(b.z*s); o[7]=f2b(b.w*s);
  *(u16x8*)(out + (size_t)row * 512 + lane * 8) = o;
}

// ---------------- CSR build, edges ordered by (row, col>>12) ----------------
__global__ __launch_bounds__(256) void hist2_k(const int* __restrict__ er, const int* __restrict__ ec,
                                               int* __restrict__ h2) {
  int i = blockIdx.x * 256 + threadIdx.x;
  if (i < N_EDGES) atomicAdd(&h2[er[i] * NCB + (ec[i] >> 12)], 1);
}

__global__ __launch_bounds__(256) void scan1_k(const int* __restrict__ deg, int* __restrict__ out,
                                               int* __restrict__ csum, int n) {
  __shared__ int sd[256];
  int t = threadIdx.x;
  int base = blockIdx.x * 1024;
  int v[4], s = 0;
#pragma unroll
  for (int j = 0; j < 4; ++j) {
    int idx = base + t * 4 + j;
    v[j] = (idx < n) ? deg[idx] : 0;
    s += v[j];
  }
  sd[t] = s;
  __syncthreads();
  for (int off = 1; off < 256; off <<= 1) {
    int xx = (t >= off) ? sd[t - off] : 0;
    __syncthreads();
    sd[t] += xx;
    __syncthreads();
  }
  if (t == 255) csum[blockIdx.x] = sd[255];
  int run = sd[t] - s;
#pragma unroll
  for (int j = 0; j < 4; ++j) {
    int idx = base + t * 4 + j;
    if (idx < n) out[idx] = run;
    run += v[j];
  }
}

// single-block parallel exclusive scan, n <= 768
__global__ __launch_bounds__(256) void scan2p_k(int* __restrict__ csum, int n) {
  __shared__ int sd[256];
  int t = threadIdx.x;
  int v[3], s = 0;
#pragma unroll
  for (int j = 0; j < 3; ++j) {
    int idx = t * 3 + j;
    v[j] = (idx < n) ? csum[idx] : 0;
    s += v[j];
  }
  sd[t] = s;
  __syncthreads();
  for (int off = 1; off < 256; off <<= 1) {
    int xx = (t >= off) ? sd[t - off] : 0;
    __syncthreads();
    sd[t] += xx;
    __syncthreads();
  }
  int run = sd[t] - s;
#pragma unroll
  for (int j = 0; j < 3; ++j) {
    int idx = t * 3 + j;
    if (idx < n) csum[idx] = run;
    run += v[j];
  }
}

__global__ __launch_bounds__(256) void scan3_k(int* __restrict__ out, const int* __restrict__ csum, int n) {
  int i = blockIdx.x * 256 + threadIdx.x;
  if (i < n) out[i] += csum[i >> 10];
}

__global__ __launch_bounds__(256) void extract_k(const int* __restrict__ rs2c, int* __restrict__ rs_s,
                                                 int* __restrict__ rs2w) {
  int i = blockIdx.x * 256 + threadIdx.x;
  if (i < N_NODES) rs_s[i] = rs2c[i * NCB];
  if (i == N_NODES) {
    rs_s[i] = N_EDGES;
    rs2w[(size_t)N_NODES * NCB] = N_EDGES;  // sentinel for (row=last, cb=last)
  }
}

__global__ __launch_bounds__(256) void scatter2_k(const int* __restrict__ er, const int* __restrict__ ec,
    const float* __restrict__ ev, int* __restrict__ head2, int2* __restrict__ ep) {
  int i = blockIdx.x * 256 + threadIdx.x;
  if (i < N_EDGES) {
    int r = er[i], c = ec[i];
    int p = atomicAdd(&head2[r * NCB + (c >> 12)], 1);
    ep[p] = make_int2(c, __float_as_int(ev[i]));
  }
}

// ---------------- all three W [K,N] fp32 -> WT [N,K] bf16, one launch ----------------
__global__ __launch_bounds__(256) void wconv3_k(const float* __restrict__ W0f,
                                                const float* __restrict__ W1f,
                                                const float* __restrict__ W2f,
                                                unsigned short* __restrict__ w0t,
                                                unsigned short* __restrict__ w1t,
                                                unsigned short* __restrict__ w2t) {
  const int S0 = 512 * 2048;   // 1048576
  const int S1 = 2048 * 1024;  // 2097152
  const int S2 = 1024 * 512;   // 524288
  int i = blockIdx.x * 256 + threadIdx.x;
  if (i < S0) {
    int n = i / 512, k = i - n * 512;
    w0t[i] = f2b(W0f[(size_t)k * 2048 + n]);
  } else if (i < S0 + S1) {
    int j = i - S0;
    int n = j / 2048, k = j - n * 2048;
    w1t[j] = f2b(W1f[(size_t)k * 1024 + n]);
  } else if (i < S0 + S1 + S2) {
    int j = i - S0 - S1;
    int n = j / 1024, k = j - n * 1024;
    w2t[j] = f2b(W2f[(size_t)k * 512 + n]);
  }
}

// ---------------- feature-chunked, phase-synced CSR SpMM ----------------
// blockIdx%8 = feature chunk (steers chunk c to XCD c): per-XCD gather table is
// D/8 feats wide (1 MB col-block slice @ D=1024), reuse/slice-row ~30x vs 4x.
// cb-outer / row-inner (8 rows per wave, acc in VGPRs) keeps resident waves on
// the same col-block slice; edge order per (row,feat) identical to the sorted
// CSR sweep, so summation order (and absmax) is unchanged.
// Columns defensively clamped to [0, N_NODES): indexing bugs read in-bounds
// (absmax failure with counters) instead of faulting on poisoned workspace.
// MODE 0: D=512 raw bf16. MODE 1: D=1024 bias+leakyrelu bf16. MODE 2: D=512 bias fp32.
template <int D, int MODE>
__global__ __launch_bounds__(256) void spmm_c_k(const unsigned short* __restrict__ in,
    const int* __restrict__ rs2, const int2* __restrict__ ep,
    const float* __restrict__ bias, void* __restrict__ outv) {
  constexpr int CF = D / 8;      // chunk feats: 128 (D=1024) or 64 (D=512)
  constexpr int FPL = CF / 64;   // feats per lane: 2 or 1
  int lane = threadIdx.x & 63;
  int wid = threadIdx.x >> 6;
  int chunk = blockIdx.x & 7;
  int rowg = blockIdx.x >> 3;
  int rbase = (rowg * 4 + wid) * 8;
  float acc[8][FPL];
#pragma unroll
  for (int j = 0; j < 8; ++j)
#pragma unroll
    for (int f = 0; f < FPL; ++f) acc[j][f] = 0.f;
  const char* hb = (const char*)in + (chunk * CF + lane * FPL) * 2;
  const unsigned int rowBytes = D * 2;

  for (int cb = 0; cb < NCB; ++cb) {
#pragma unroll 1
    for (int j = 0; j < 8; ++j) {
      int row = rbase + j;
      if (row >= N_NODES) continue;
      int e0 = rs2[row * NCB + cb];
      int e1 = rs2[row * NCB + cb + 1];
      int e = e0;
      for (; e + 2 <= e1; e += 2) {
        int2 pa = ep[e];
        int2 pb = ep[e + 1];
        unsigned ca = (unsigned)pa.x < N_NODES ? (unsigned)pa.x : 0u;
        unsigned cb2 = (unsigned)pb.x < N_NODES ? (unsigned)pb.x : 0u;
        float va = __int_as_float(pa.y);
        float vb = __int_as_float(pb.y);
        if (FPL == 2) {
          unsigned int wa = *(const unsigned int*)(hb + (size_t)(ca * rowBytes));
          unsigned int wb = *(const unsigned int*)(hb + (size_t)(cb2 * rowBytes));
          union { unsigned int i; float f; } l0, h0, l1, h1;
          l0.i = wa << 16; h0.i = wa & 0xffff0000u;
          l1.i = wb << 16; h1.i = wb & 0xffff0000u;
          acc[j][0] = fmaf(va, l0.f, acc[j][0]);
          acc[j][1] = fmaf(va, h0.f, acc[j][1]);
          acc[j][0] = fmaf(vb, l1.f, acc[j][0]);
          acc[j][1] = fmaf(vb, h1.f, acc[j][1]);
        } else {
          float f0 = b2f(*(const unsigned short*)(hb + (size_t)(ca * rowBytes)));
          float f1 = b2f(*(const unsigned short*)(hb + (size_t)(cb2 * rowBytes)));
          acc[j][0] = fmaf(va, f0, acc[j][0]);
          acc[j][0] = fmaf(vb, f1, acc[j][0]);
        }
      }
      if (e < e1) {
        int2 p = ep[e];
        unsigned c = (unsigned)p.x < N_NODES ? (unsigned)p.x : 0u;
        float v = __int_as_float(p.y);
        if (FPL == 2) {
          unsigned int w = *(const unsigned int*)(hb + (size_t)(c * rowBytes));
          union { unsigned int i; float f; } lo, hi;
          lo.i = w << 16; hi.i = w & 0xffff0000u;
          acc[j][0] = fmaf(v, lo.f, acc[j][0]);
          acc[j][1] = fmaf(v, hi.f, acc[j][1]);
        } else {
          float f0 = b2f(*(const unsigned short*)(hb + (size_t)(c * rowBytes)));
          acc[j][0] = fmaf(v, f0, acc[j][0]);
        }
      }
    }
  }

#pragma unroll 1
  for (int j = 0; j < 8; ++j) {
    int row = rbase + j;
    if (row >= N_NODES) continue;
    if (MODE == 2) {
      float* out = (float*)outv;
      out[(size_t)row * D + chunk * CF + lane] = acc[j][0] + bias[chunk * CF + lane];
    } else if (MODE == 1) {
      int fb = chunk * CF + lane * 2;
      float x0 = acc[j][0] + bias[fb];
      float x1 = acc[j][1] + bias[fb + 1];
      x0 = x0 >= 0.f ? x0 : 0.2f * x0;
      x1 = x1 >= 0.f ? x1 : 0.2f * x1;
      unsigned int o = (unsigned int)f2b(x0) | ((unsigned int)f2b(x1) << 16);
      *(unsigned int*)((unsigned short*)outv + (size_t)row * D + fb) = o;
    } else {
      ((unsigned short*)outv)[(size_t)row * D + chunk * CF + lane] = f2b(acc[j][0]);
    }
  }
}

// ---------------- bf16 MFMA GEMM: C[M,N] = A[M,K] * BT[N,K]^T ----------------
// 1-D grid; bijective XCD chunking + 8-tile-row supertiles (kept from R2).
template <bool BIAS_RELU>
__global__ __launch_bounds__(256) void gemm_bt_k(
    const unsigned short* __restrict__ A, const unsigned short* __restrict__ BT,
    const float* __restrict__ bias, unsigned short* __restrict__ C,
    int M, int N, int K, int gx) {
  __shared__ __align__(16) unsigned short sA[128 * 32];
  __shared__ __align__(16) unsigned short sB[128 * 32];
  int nwg = gridDim.x;
  int id = blockIdx.x;
  int q = nwg >> 3, r = nwg & 7;
  int xcd = id & 7, pos = id >> 3;
  int nid = (xcd < r ? xcd * (q + 1) : r * (q + 1) + (xcd - r) * q) + pos;
  const int G = 8;
  int gsz = gx * G;
  int grp = nid / gsz;
  int rem = nid - grp * gsz;
  int bx = rem % gx;
  int by = grp * G + rem / gx;

  int tid = threadIdx.x;
  int lane = tid & 63;
  int wid = tid >> 6;
  int wm = (wid & 1) * 64;
  int wn = (wid >> 1) * 64;
  int mblk = by * 128;
  int nblk = bx * 128;
  const unsigned short* Bb = BT + (size_t)nblk * K;
  int c0 = tid, c1 = tid + 256;
  int ar0 = c0 >> 2, ac0 = (c0 & 3) * 8;
  int ar1 = c1 >> 2, ac1 = (c1 & 3) * 8;
  int ra0 = mblk + ar0; if (ra0 > M - 1) ra0 = M - 1;
  int ra1 = mblk + ar1; if (ra1 > M - 1) ra1 = M - 1;
  f32x4 acc[4][4] = {};
  for (int k0 = 0; k0 < K; k0 += 32) {
    load_lds16(A + (size_t)ra0 * K + k0 + ac0, &sA[c0 * 8]);
    load_lds16(A + (size_t)ra1 * K + k0 + ac1, &sA[c1 * 8]);
    load_lds16(Bb + (size_t)ar0 * K + k0 + ac0, &sB[c0 * 8]);
    load_lds16(Bb + (size_t)ar1 * K + k0 + ac1, &sB[c1 * 8]);
    __syncthreads();
    bf16x8 af[4], bfr[4];
    int kq = (lane >> 4) * 8;
    int mr = wm + (lane & 15);
    int nr = wn + (lane & 15);
#pragma unroll
    for (int i = 0; i < 4; ++i) af[i] = *(const bf16x8*)&sA[(mr + i * 16) * 32 + kq];
#pragma unroll
    for (int j = 0; j < 4; ++j) bfr[j] = *(const bf16x8*)&sB[(nr + j * 16) * 32 + kq];
#pragma unroll
    for (int i = 0; i < 4; ++i)
#pragma unroll
      for (int j = 0; j < 4; ++j)
        acc[i][j] = __builtin_amdgcn_mfma_f32_16x16x32_bf16(af[i], bfr[j], acc[i][j], 0, 0, 0);
    __syncthreads();
  }
  int quad = lane >> 4;
  int lc = lane & 15;
#pragma unroll
  for (int i = 0; i < 4; ++i) {
#pragma unroll
    for (int r2 = 0; r2 < 4; ++r2) {
      int gm = mblk + wm + i * 16 + quad * 4 + r2;
      if (gm < M) {
#pragma unroll
        for (int j = 0; j < 4; ++j) {
          int gn = nblk + wn + j * 16 + lc;
          float v = acc[i][j][r2];
          if (BIAS_RELU) { v += bias[gn]; v = v >= 0.f ? v : 0.2f * v; }
          C[(size_t)gm * N + gn] = f2b(v);
        }
      }
    }
  }
}

extern "C" void kernel_launch(void* const* d_in, const int* in_sizes, int n_in,
                              void* d_out, int out_size, void* d_ws, size_t ws_size,
                              hipStream_t stream) {
  (void)in_sizes; (void)n_in; (void)out_size;
  const float* x  = (const float*)d_in[0];
  const int* erow = (const int*)d_in[1];
  const int* ecol = (const int*)d_in[2];
  const float* ev = (const float*)d_in[3];
  const float* W0 = (const float*)d_in[4];
  const float* b0 = (const float*)d_in[5];
  const float* W1 = (const float*)d_in[6];
  const float* b1 = (const float*)d_in[7];
  const float* W2 = (const float*)d_in[8];
  const float* b2 = (const float*)d_in[9];

  // ---- persistent meta (after the activation pool) ----
  const size_t POOL_T1 = 256000000;   // h1 full (204.8M, norm_out overlaid) + spmm0_out
  const size_t POOL_T2 = 204800000;   // norm + spmm0 + h1 half-chunk
  const size_t POOL_T3 = 153600000;   // norm + spmm0 + h1 quarter-chunk
  // ep 12.8M + rs_s 200064 + weights 7.34M + rs2 (650001 ints, padded)
  const size_t RS2_SZ = 2600128;
  const size_t META = 12800000 + 200064 + 7340032 + RS2_SZ;
  int tier = (ws_size >= POOL_T1 + META) ? 1 : (ws_size >= POOL_T2 + META) ? 2 : 3;
  size_t pool_sz = (tier == 1) ? POOL_T1 : (tier == 2) ? POOL_T2 : POOL_T3;

  char* ws = (char*)d_ws;
  int2*  ep   = (int2*)(ws + pool_sz);
  int*   rs_s = (int*)(ws + pool_sz + 12800000);
  unsigned short* w0t = (unsigned short*)(ws + pool_sz + 12800000 + 200064);
  unsigned short* w1t = w0t + (size_t)2048 * 512;
  unsigned short* w2t = w1t + (size_t)1024 * 2048;
  int*   rs2  = (int*)(ws + pool_sz + 12800000 + 200064 + 7340032);  // persistent (spmm reads it)
  // build-time transients live in the (then-dead) activation pool
  int* head2 = (int*)(ws);                  // 2.6MB
  int* csum  = (int*)(ws + 2600064);        // 4KB
  unsigned short* u = (unsigned short*)d_out;  // [N,1024] bf16 scratch

  // ---- CSR build: edges ordered by (row, col>>12) ----
  hipMemsetAsync(rs2, 0, 2600064, stream);
  hist2_k<<<6250, 256, 0, stream>>>(erow, ecol, rs2);
  scan1_k<<<635, 256, 0, stream>>>(rs2, rs2, csum, N_NODES * NCB);
  scan2p_k<<<1, 256, 0, stream>>>(csum, 635);
  scan3_k<<<2540, 256, 0, stream>>>(rs2, csum, N_NODES * NCB);
  extract_k<<<196, 256, 0, stream>>>(rs2, rs_s, rs2);
  hipMemcpyAsync(head2, rs2, (size_t)N_NODES * NCB * 4, hipMemcpyDeviceToDevice, stream);
  scatter2_k<<<6250, 256, 0, stream>>>(erow, ecol, ev, head2, ep);

  // ---- weights -> transposed bf16 (single launch) ----
  wconv3_k<<<14336, 256, 0, stream>>>(W0, W1, W2, w0t, w1t, w2t);

  const int SPMM_GRID = 8 * 1563;  // 8 chunks x ceil(50000/32) row-groups

  if (tier == 1) {
    unsigned short* h1        = (unsigned short*)(ws);              // 204.8M
    unsigned short* norm_out  = (unsigned short*)(ws);              // overlays h1 (dead before h1 written)
    unsigned short* spmm0_out = (unsigned short*)(ws + 204800000);  // 51.2M
    unsigned short* h2        = (unsigned short*)(ws);              // overlays h1 (dead)
    unsigned short* vbuf      = (unsigned short*)(ws + 102400000);
    normalize_k<<<12500, 256, 0, stream>>>(x, norm_out);
    spmm_c_k<512, 0><<<SPMM_GRID, 256, 0, stream>>>(norm_out, rs2, ep, nullptr, spmm0_out);
    gemm_bt_k<true ><<<16 * 391, 256, 0, stream>>>(spmm0_out, w0t, b0, h1, N_NODES, 2048, 512, 16);
    gemm_bt_k<false><<<8 * 391, 256, 0, stream>>>(h1, w1t, nullptr, u, N_NODES, 1024, 2048, 8);
    spmm_c_k<1024, 1><<<SPMM_GRID, 256, 0, stream>>>(u, rs2, ep, b1, h2);
    gemm_bt_k<false><<<4 * 391, 256, 0, stream>>>(h2, w2t, nullptr, vbuf, N_NODES, 512, 1024, 4);
    spmm_c_k<512, 2><<<SPMM_GRID, 256, 0, stream>>>(vbuf, rs2, ep, b2, (float*)d_out);
  } else {
    int nchunk = (tier == 2) ? 2 : 4;
    int crows = (tier == 2) ? 25000 : 12500;
    int ytiles = (tier == 2) ? 196 : 98;
    unsigned short* norm_out  = (unsigned short*)(ws);
    unsigned short* spmm0_out = (unsigned short*)(ws + 51200000);
    unsigned short* h1chunk   = (unsigned short*)(ws + 102400000);
    unsigned short* h2        = (unsigned short*)(ws);
    unsigned short* vbuf      = (unsigned short*)(ws + 102400000);
    normalize_k<<<12500, 256, 0, stream>>>(x, norm_out);
    spmm_c_k<512, 0><<<SPMM_GRID, 256, 0, stream>>>(norm_out, rs2, ep, nullptr, spmm0_out);
    for (int c = 0; c < nchunk; ++c) {
      const unsigned short* a0 = spmm0_out + (size_t)c * crows * 512;
      unsigned short* uc = u + (size_t)c * crows * 1024;
      gemm_bt_k<true ><<<16 * ytiles, 256, 0, stream>>>(a0, w0t, b0, h1chunk, crows, 2048, 512, 16);
      gemm_bt_k<false><<<8 * ytiles, 256, 0, stream>>>(h1chunk, w1t, nullptr, uc, crows, 1024, 2048, 8);
    }
    spmm_c_k<1024, 1><<<SPMM_GRID, 256, 0, stream>>>(u, rs2, ep, b1, h2);
    gemm_bt_k<false><<<4 * 391, 256, 0, stream>>>(h2, w2t, nullptr, vbuf, N_NODES, 512, 1024, 4);
    spmm_c_k<512, 2><<<SPMM_GRID, 256, 0, stream>>>(vbuf, rs2, ep, b2, (float*)d_out);
  }
}